// Round 1
// baseline (140.547 us; speedup 1.0000x reference)
//
#include <hip/hip_runtime.h>
#include <cstdint>

// Problem constants (match reference)
static constexpr float kThresh = 0.65f;

struct Accum {
  unsigned long long lossFixed; // signed fixed-point (<<20), two's-complement in u64
  int cnt;   // # rows with !useR
  int minK;  // first row index with useL (B if none)
  int tl;    // any targets[:, :3] > 0
  int tr;    // any targets[:, 3:] > 0
};

__global__ void init_acc(Accum* acc, int B) {
  acc->lossFixed = 0ull;
  acc->cnt = 0;
  acc->minK = B;
  acc->tl = 0;
  acc->tr = 0;
}

__device__ __forceinline__ void row_op(
    const float p[6], const float t[6], int row,
    float& lossSum, int& cnt, int& minK, int& tl, int& tr) {
  // sigmoid is monotone: max of sigmoids = sigmoid of max
  float mR = fmaxf(fmaxf(p[0], p[1]), p[2]);
  float mL = fmaxf(fmaxf(p[3], p[4]), p[5]);
  float sR = 1.0f / (1.0f + __expf(-mR));
  float sL = 1.0f / (1.0f + __expf(-mL));
  bool rs = sR > kThresh;
  bool ls = sL > kThresh;
  bool none = (!rs) && (!ls);
  bool rwins = sR > sL;
  bool useR = rs || (none && rwins);
  bool useL = ls || (none && !rwins);
  if (!useR) cnt++;
  if (useL && row < minK) minK = row;
  float tsumL = t[0] + t[1] + t[2];
  float tsumR = t[3] + t[4] + t[5];
  if (tsumL > 0.0f) tl = 1;
  if (tsumR > 0.0f) tr = 1;
  // cross-entropy: sum_j t_j * (lse - p_j)
  float m = fmaxf(mR, mL);
  float se = 0.0f, tp = 0.0f, ts = 0.0f;
#pragma unroll
  for (int j = 0; j < 6; ++j) {
    se += __expf(p[j] - m);
    tp += t[j] * p[j];
    ts += t[j];
  }
  float lse = m + __logf(se);
  lossSum += lse * ts - tp;
}

__global__ __launch_bounds__(256) void loss_main(
    const float* __restrict__ preds, const float* __restrict__ targets,
    int npairs, Accum* __restrict__ acc) {
  int tid = blockIdx.x * blockDim.x + threadIdx.x;
  int stride = gridDim.x * blockDim.x;
  float lossSum = 0.0f;
  int cnt = 0;
  int minK = 0x7fffffff;
  int tl = 0, tr = 0;

  for (int q = tid; q < npairs; q += stride) {
    size_t base = (size_t)q * 12;  // 2 rows = 12 floats = 48 B (16B-aligned)
    float4 a  = *reinterpret_cast<const float4*>(preds + base);
    float4 b  = *reinterpret_cast<const float4*>(preds + base + 4);
    float4 c  = *reinterpret_cast<const float4*>(preds + base + 8);
    float4 ta = *reinterpret_cast<const float4*>(targets + base);
    float4 tb = *reinterpret_cast<const float4*>(targets + base + 4);
    float4 tc = *reinterpret_cast<const float4*>(targets + base + 8);
    {
      float p[6] = {a.x, a.y, a.z, a.w, b.x, b.y};
      float t[6] = {ta.x, ta.y, ta.z, ta.w, tb.x, tb.y};
      row_op(p, t, 2 * q, lossSum, cnt, minK, tl, tr);
    }
    {
      float p[6] = {b.z, b.w, c.x, c.y, c.z, c.w};
      float t[6] = {tb.z, tb.w, tc.x, tc.y, tc.z, tc.w};
      row_op(p, t, 2 * q + 1, lossSum, cnt, minK, tl, tr);
    }
  }

  // wave-64 butterfly/shift reduction
#pragma unroll
  for (int off = 32; off > 0; off >>= 1) {
    lossSum += __shfl_down(lossSum, off);
    cnt     += __shfl_down(cnt, off);
    minK    = min(minK, __shfl_down(minK, off));
    tl      |= __shfl_down(tl, off);
    tr      |= __shfl_down(tr, off);
  }

  __shared__ float wLoss[4];
  __shared__ int wCnt[4], wMinK[4], wTl[4], wTr[4];
  int wave = threadIdx.x >> 6;
  int lane = threadIdx.x & 63;
  if (lane == 0) {
    wLoss[wave] = lossSum; wCnt[wave] = cnt; wMinK[wave] = minK;
    wTl[wave] = tl; wTr[wave] = tr;
  }
  __syncthreads();
  if (threadIdx.x == 0) {
    float L = wLoss[0] + wLoss[1] + wLoss[2] + wLoss[3];
    int Cn  = wCnt[0] + wCnt[1] + wCnt[2] + wCnt[3];
    int K   = min(min(wMinK[0], wMinK[1]), min(wMinK[2], wMinK[3]));
    int Tl  = wTl[0] | wTl[1] | wTl[2] | wTl[3];
    int Tr  = wTr[0] | wTr[1] | wTr[2] | wTr[3];
    long long fx = llrintf(L * 1048576.0f);  // <<20 fixed point, deterministic
    atomicAdd(&acc->lossFixed, (unsigned long long)fx);
    if (Cn) atomicAdd(&acc->cnt, Cn);
    atomicMin(&acc->minK, K);
    if (Tl) atomicOr(&acc->tl, 1);
    if (Tr) atomicOr(&acc->tr, 1);
  }
}

__global__ void finalize_kernel(const Accum* __restrict__ acc,
                                float* __restrict__ out, int B) {
  double s = (double)(long long)acc->lossFixed / 1048576.0;
  double base = s / (double)B;
  double pen = 0.1 * ((acc->tl ? (double)acc->cnt : 0.0) +
                      (acc->tr ? (double)acc->minK : 0.0));
  out[0] = (float)(base + pen);
}

extern "C" void kernel_launch(void* const* d_in, const int* in_sizes, int n_in,
                              void* d_out, int out_size, void* d_ws, size_t ws_size,
                              hipStream_t stream) {
  const float* preds   = (const float*)d_in[0];
  const float* targets = (const float*)d_in[1];
  float* out = (float*)d_out;
  Accum* acc = (Accum*)d_ws;

  int B = in_sizes[0] / 6;
  int npairs = B / 2;

  hipLaunchKernelGGL(init_acc, dim3(1), dim3(1), 0, stream, acc, B);
  hipLaunchKernelGGL(loss_main, dim3(2048), dim3(256), 0, stream,
                     preds, targets, npairs, acc);
  hipLaunchKernelGGL(finalize_kernel, dim3(1), dim3(1), 0, stream, acc, out, B);
}

// Round 2
// 38.847 us; speedup vs baseline: 3.6179x; 3.6179x over previous
//
#include <hip/hip_runtime.h>
#include <cstdint>
#include <climits>

// ln(0.65/0.35): sigmoid(m) > 0.65  <=>  m > logit(0.65)  (strict monotone)
static constexpr float kLogitThresh = 0.61903920840622351f;
static constexpr int NB = 2048;  // blocks in main kernel

__device__ __forceinline__ void row_op(
    const float p[6], const float t[6], int row,
    float& lossSum, int& cnt, int& minK, int& tl, int& tr) {
  float mR = fmaxf(fmaxf(p[0], p[1]), p[2]);
  float mL = fmaxf(fmaxf(p[3], p[4]), p[5]);
  // all flag logic in logit space (sigmoid is strictly monotone)
  bool rs = mR > kLogitThresh;
  bool ls = mL > kLogitThresh;
  bool none = (!rs) && (!ls);
  bool rwins = mR > mL;
  bool useR = rs || (none && rwins);
  bool useL = ls || (none && !rwins);
  if (!useR) cnt++;
  if (useL && row < minK) minK = row;
  float tsumL = t[0] + t[1] + t[2];
  float tsumR = t[3] + t[4] + t[5];
  if (tsumL > 0.0f) tl = 1;
  if (tsumR > 0.0f) tr = 1;
  // cross-entropy: sum_j t_j * (lse - p_j)
  float m = fmaxf(mR, mL);
  float se = 0.0f, tp = 0.0f, ts = 0.0f;
#pragma unroll
  for (int j = 0; j < 6; ++j) {
    se += __expf(p[j] - m);
    tp += t[j] * p[j];
    ts += t[j];
  }
  float lse = m + __logf(se);
  lossSum += lse * ts - tp;
}

__global__ __launch_bounds__(256) void loss_main(
    const float* __restrict__ preds, const float* __restrict__ targets,
    int npairs,
    float* __restrict__ pLoss, int* __restrict__ pCnt,
    int* __restrict__ pMinK, int* __restrict__ pTl, int* __restrict__ pTr) {
  int tid = blockIdx.x * blockDim.x + threadIdx.x;
  int stride = gridDim.x * blockDim.x;
  float lossSum = 0.0f;
  int cnt = 0;
  int minK = INT_MAX;
  int tl = 0, tr = 0;

  for (int q = tid; q < npairs; q += stride) {
    size_t base = (size_t)q * 12;  // 2 rows = 12 floats = 48 B (16B aligned)
    float4 a  = *reinterpret_cast<const float4*>(preds + base);
    float4 b  = *reinterpret_cast<const float4*>(preds + base + 4);
    float4 c  = *reinterpret_cast<const float4*>(preds + base + 8);
    float4 ta = *reinterpret_cast<const float4*>(targets + base);
    float4 tb = *reinterpret_cast<const float4*>(targets + base + 4);
    float4 tc = *reinterpret_cast<const float4*>(targets + base + 8);
    {
      float p[6] = {a.x, a.y, a.z, a.w, b.x, b.y};
      float t[6] = {ta.x, ta.y, ta.z, ta.w, tb.x, tb.y};
      row_op(p, t, 2 * q, lossSum, cnt, minK, tl, tr);
    }
    {
      float p[6] = {b.z, b.w, c.x, c.y, c.z, c.w};
      float t[6] = {tb.z, tb.w, tc.x, tc.y, tc.z, tc.w};
      row_op(p, t, 2 * q + 1, lossSum, cnt, minK, tl, tr);
    }
  }

  // wave-64 shift reduction
#pragma unroll
  for (int off = 32; off > 0; off >>= 1) {
    lossSum += __shfl_down(lossSum, off);
    cnt     += __shfl_down(cnt, off);
    minK    = min(minK, __shfl_down(minK, off));
    tl      |= __shfl_down(tl, off);
    tr      |= __shfl_down(tr, off);
  }

  __shared__ float wLoss[4];
  __shared__ int wCnt[4], wMinK[4], wTl[4], wTr[4];
  int wave = threadIdx.x >> 6;
  int lane = threadIdx.x & 63;
  if (lane == 0) {
    wLoss[wave] = lossSum; wCnt[wave] = cnt; wMinK[wave] = minK;
    wTl[wave] = tl; wTr[wave] = tr;
  }
  __syncthreads();
  if (threadIdx.x == 0) {
    // plain stores to per-block slots — NO atomics, no shared cache line
    pLoss[blockIdx.x] = wLoss[0] + wLoss[1] + wLoss[2] + wLoss[3];
    pCnt[blockIdx.x]  = wCnt[0] + wCnt[1] + wCnt[2] + wCnt[3];
    pMinK[blockIdx.x] = min(min(wMinK[0], wMinK[1]), min(wMinK[2], wMinK[3]));
    pTl[blockIdx.x]   = wTl[0] | wTl[1] | wTl[2] | wTl[3];
    pTr[blockIdx.x]   = wTr[0] | wTr[1] | wTr[2] | wTr[3];
  }
}

__global__ __launch_bounds__(256) void reduce_final(
    const float* __restrict__ pLoss, const int* __restrict__ pCnt,
    const int* __restrict__ pMinK, const int* __restrict__ pTl,
    const int* __restrict__ pTr, float* __restrict__ out, int B) {
  double L = 0.0;
  int cnt = 0, mk = INT_MAX, tl = 0, tr = 0;
  for (int i = threadIdx.x; i < NB; i += 256) {
    L   += (double)pLoss[i];
    cnt += pCnt[i];
    mk   = min(mk, pMinK[i]);
    tl  |= pTl[i];
    tr  |= pTr[i];
  }
#pragma unroll
  for (int off = 32; off > 0; off >>= 1) {
    L   += __shfl_down(L, off);
    cnt += __shfl_down(cnt, off);
    mk   = min(mk, __shfl_down(mk, off));
    tl  |= __shfl_down(tl, off);
    tr  |= __shfl_down(tr, off);
  }
  __shared__ double sL[4];
  __shared__ int sC[4], sM[4], sT[4], sR[4];
  int wave = threadIdx.x >> 6;
  int lane = threadIdx.x & 63;
  if (lane == 0) {
    sL[wave] = L; sC[wave] = cnt; sM[wave] = mk; sT[wave] = tl; sR[wave] = tr;
  }
  __syncthreads();
  if (threadIdx.x == 0) {
    double Lt = sL[0] + sL[1] + sL[2] + sL[3];
    int Cn = sC[0] + sC[1] + sC[2] + sC[3];
    int K  = min(min(sM[0], sM[1]), min(sM[2], sM[3]));
    int Tl = sT[0] | sT[1] | sT[2] | sT[3];
    int Tr = sR[0] | sR[1] | sR[2] | sR[3];
    if (K > B) K = B;
    double base = Lt / (double)B;
    double pen = 0.1 * ((Tl ? (double)Cn : 0.0) + (Tr ? (double)K : 0.0));
    out[0] = (float)(base + pen);
  }
}

extern "C" void kernel_launch(void* const* d_in, const int* in_sizes, int n_in,
                              void* d_out, int out_size, void* d_ws, size_t ws_size,
                              hipStream_t stream) {
  const float* preds   = (const float*)d_in[0];
  const float* targets = (const float*)d_in[1];
  float* out = (float*)d_out;

  // SoA partials in workspace: 5 arrays of NB elements (40 KB)
  float* pLoss = (float*)d_ws;
  int*   pCnt  = (int*)((char*)d_ws + NB * 4);
  int*   pMinK = (int*)((char*)d_ws + NB * 8);
  int*   pTl   = (int*)((char*)d_ws + NB * 12);
  int*   pTr   = (int*)((char*)d_ws + NB * 16);

  int B = in_sizes[0] / 6;
  int npairs = B / 2;

  hipLaunchKernelGGL(loss_main, dim3(NB), dim3(256), 0, stream,
                     preds, targets, npairs, pLoss, pCnt, pMinK, pTl, pTr);
  hipLaunchKernelGGL(reduce_final, dim3(1), dim3(256), 0, stream,
                     pLoss, pCnt, pMinK, pTl, pTr, out, B);
}